// Round 5
// baseline (1695.105 us; speedup 1.0000x reference)
//
#include <hip/hip_runtime.h>
#include <hip/hip_bf16.h>

#define N_VOX 200000
#define KOFF 27
#define PPK 100000
#define C 64
#define BN_EPS 1e-5f

#define NBLK 782                      // ceil(N_VOX/256) out-voxel blocks
#define NKEY (NBLK * KOFF)            // 21114 (block,k) runs
#define NPAIR (KOFF * PPK)            // 2.7M
#define PADMAX (NPAIR + NKEY * 15)    // 3,016,710 max padded slots

typedef __bf16 bf16x8 __attribute__((ext_vector_type(8)));
typedef __bf16 bf16x4 __attribute__((ext_vector_type(4)));
typedef float f32x4 __attribute__((ext_vector_type(4)));

// ---------------------------------------------------------------------------
// features fp32 -> bf16 (RNE), vectorized. Row N_VOX is a zero dummy row
// (memset by host) used by padded slots.
// ---------------------------------------------------------------------------
__global__ __launch_bounds__(256)
void convert_features(const float* __restrict__ f, __bf16* __restrict__ fb)
{
    const size_t total4 = (size_t)N_VOX * C / 4;
    const size_t i = (size_t)blockIdx.x * blockDim.x + threadIdx.x;
    if (i >= total4) return;
    const float4 v = ((const float4*)f)[i];
    bf16x4 o;
    o.x = (__bf16)v.x; o.y = (__bf16)v.y; o.z = (__bf16)v.z; o.w = (__bf16)v.w;
    ((bf16x4*)fb)[i] = o;
}

// weight [k][cin][cout] fp32 -> wt [k][cout][cin] bf16 (transposed).
__global__ __launch_bounds__(256)
void convert_weight(const float* __restrict__ w, __bf16* __restrict__ wt)
{
    const int k = blockIdx.x;
    const float* W = w + (size_t)k * C * C;
    __bf16* Wt = wt + (size_t)k * C * C;
    for (int idx = threadIdx.x; idx < C * C; idx += 256) {
        const int ci = idx >> 6, co = idx & 63;
        Wt[co * C + ci] = (__bf16)W[idx];
    }
}

// ===========================================================================
// Pair sort by (out_block, k): histogram over 21114 bins -> padded scan
// (each run padded to x16 for whole MFMA tiles) -> scatter of
// (in_row u32, out_local u8). Replaces the entire per-chunk partial-buffer
// pipeline of rounds 1-4.
// ===========================================================================
__global__ __launch_bounds__(256)
void hist2(const int* __restrict__ out_idx, unsigned* __restrict__ counts)
{
    const int i = blockIdx.x * 256 + threadIdx.x;
    if (i < NPAIR) {
        const int o = out_idx[i];
        const int k = i / PPK;
        atomicAdd(&counts[(o >> 8) * KOFF + k], 1u);
    }
}

// single-block scan of padded counts -> soff[NKEY+1]; also seeds cursor.
__global__ __launch_bounds__(256)
void scan_pad(const unsigned* __restrict__ counts, unsigned* __restrict__ soff,
              unsigned* __restrict__ cursor)
{
    __shared__ unsigned sdata[256];
    const int t = threadIdx.x;
    const int CH = (NKEY + 255) / 256;   // 83
    const int i0 = t * CH;
    unsigned s = 0;
    for (int j = 0; j < CH; ++j) {
        const int i = i0 + j;
        if (i < NKEY) s += ((counts[i] + 15u) & ~15u);
    }
    sdata[t] = s;
    __syncthreads();
    for (int off = 1; off < 256; off <<= 1) {
        const unsigned a = (t >= off) ? sdata[t - off] : 0u;
        __syncthreads();
        sdata[t] += a;
        __syncthreads();
    }
    unsigned run = sdata[t] - s;   // exclusive prefix
    for (int j = 0; j < CH; ++j) {
        const int i = i0 + j;
        if (i < NKEY) {
            soff[i] = run;
            cursor[i] = run;
            run += ((counts[i] + 15u) & ~15u);
        }
    }
    if (t == 255) soff[NKEY] = run;
}

// pre-fill padded slots with dummy (in=N_VOX zero row, ol=0).
__global__ __launch_bounds__(256)
void fill_kernel(unsigned* __restrict__ sorted_in, unsigned char* __restrict__ sorted_ol)
{
    const int i = blockIdx.x * 256 + threadIdx.x;
    if (i < PADMAX) { sorted_in[i] = N_VOX; sorted_ol[i] = 0; }
}

__global__ __launch_bounds__(256)
void scatter_kernel(const int* __restrict__ out_idx, const int* __restrict__ in_idx,
                    unsigned* __restrict__ cursor, unsigned* __restrict__ sorted_in,
                    unsigned char* __restrict__ sorted_ol)
{
    const int i = blockIdx.x * 256 + threadIdx.x;
    if (i < NPAIR) {
        const int o = out_idx[i];
        const int k = i / PPK;
        const unsigned pos = atomicAdd(&cursor[(o >> 8) * KOFF + k], 1u);
        sorted_in[pos] = (unsigned)in_idx[i];
        sorted_ol[pos] = (unsigned char)(o & 255);
    }
}

// ===========================================================================
// FUSED conv+reduce+stats: block owns 256 out voxels, f32 accumulation in
// 64KB LDS via ds_add_f32 (LDS atomics: ~194M adds device-wide ~ 10us, vs
// 575us for the same count of global f32 atomics in the round-0 baseline).
// Pairs are pre-sorted by (block, k): per k-run, 16-pair MFMA tiles (padded
// with zero-row dummies). NO partial buffer, NO reduce pass, NO stats pass.
// Tiles round-robin across 8 waves via global-tile parity.
// A-frag gathered per-lane straight from featb (no LDS staging, no barrier).
// ds_add layout: quad writes 16 consecutive dwords -> conflict-free.
// ===========================================================================
__global__ __launch_bounds__(512)
void conv_fused(const __bf16* __restrict__ featb, const __bf16* __restrict__ wtb,
                const unsigned* __restrict__ sorted_in,
                const unsigned char* __restrict__ sorted_ol,
                const unsigned* __restrict__ soff,
                float* __restrict__ out, float* __restrict__ stats)
{
    __shared__ float sout[256 * C];      // 64 KB accumulator tile
    __shared__ unsigned skoff[KOFF + 1];
    __shared__ float sstat[1024];

    const int b = blockIdx.x;
    const int t = threadIdx.x;

    {   // zero the accumulator
        f32x4* p = (f32x4*)sout;
        for (int i = t; i < 256 * C / 4; i += 512) p[i] = (f32x4){0.f, 0.f, 0.f, 0.f};
    }
    if (t < KOFF + 1) skoff[t] = soff[b * KOFF + t];
    __syncthreads();

    const int wave = t >> 6;
    const int lane = t & 63;
    const int m16 = lane & 15;
    const int quad = lane >> 4;

    int ctile = 0;
    for (int k = 0; k < KOFF; ++k) {
        const unsigned rb = skoff[k];
        const int ntk = (int)((skoff[k + 1] - rb) >> 4);
        int lt = (wave - ctile) & 7;        // tiles with global parity == wave
        ctile += ntk;
        if (lt >= ntk) continue;

        // B fragments for this k (L2-resident 8KB)
        const __bf16* Wt = wtb + (size_t)k * C * C;
        bf16x8 bfrag[4][2];
#pragma unroll
        for (int nt = 0; nt < 4; ++nt)
#pragma unroll
            for (int kc = 0; kc < 2; ++kc)
                bfrag[nt][kc] = *(const bf16x8*)(Wt + (nt * 16 + m16) * C + kc * 32 + quad * 8);

        // prefetch first tile's A-row index
        unsigned rowA = sorted_in[rb + ((unsigned)lt << 4) + m16];
        for (; lt < ntk; ) {
            const unsigned tb = rb + ((unsigned)lt << 4);
            // A fragments: lane (m16,quad) reads 16B of row rowA per kc
            const __bf16* fr = featb + (size_t)rowA * C + quad * 8;
            const bf16x8 a0 = *(const bf16x8*)(fr);
            const bf16x8 a1 = *(const bf16x8*)(fr + 32);
            // out-local rows for this quad's 4 accumulator rows
            const int ol0 = sorted_ol[tb + quad * 4 + 0];
            const int ol1 = sorted_ol[tb + quad * 4 + 1];
            const int ol2 = sorted_ol[tb + quad * 4 + 2];
            const int ol3 = sorted_ol[tb + quad * 4 + 3];

            lt += 8;
            if (lt < ntk)   // break idx->gather chain across iterations
                rowA = sorted_in[rb + ((unsigned)lt << 4) + m16];

            f32x4 acc[4] = {};
#pragma unroll
            for (int nt = 0; nt < 4; ++nt) {
                acc[nt] = __builtin_amdgcn_mfma_f32_16x16x32_bf16(a0, bfrag[nt][0], acc[nt], 0, 0, 0);
                acc[nt] = __builtin_amdgcn_mfma_f32_16x16x32_bf16(a1, bfrag[nt][1], acc[nt], 0, 0, 0);
            }
            // LDS accumulate: channel c = nt*16+m16 (true order), row ol
#pragma unroll
            for (int nt = 0; nt < 4; ++nt) {
                atomicAdd(&sout[ol0 * C + nt * 16 + m16], acc[nt][0]);
                atomicAdd(&sout[ol1 * C + nt * 16 + m16], acc[nt][1]);
                atomicAdd(&sout[ol2 * C + nt * 16 + m16], acc[nt][2]);
                atomicAdd(&sout[ol3 * C + nt * 16 + m16], acc[nt][3]);
            }
        }
    }
    __syncthreads();

    // write final rows + per-channel stats partials
    const int row_cap = min(256, N_VOX - b * 256);
    const int c = t & 63;
    const int r0 = t >> 6;
    float s = 0.f, q = 0.f;
    for (int r = r0; r < row_cap; r += 8) {
        const float v = sout[r * C + c];
        out[((size_t)(b * 256 + r)) * C + c] = v;
        s += v; q += v * v;
    }
    sstat[t] = s;
    sstat[512 + t] = q;
    __syncthreads();
    if (t < C) {
        float ssum = 0.f, sq = 0.f;
#pragma unroll
        for (int u = 0; u < 8; ++u) {
            ssum += sstat[u * 64 + t];
            sq   += sstat[512 + u * 64 + t];
        }
        unsafeAtomicAdd(&stats[t], ssum);
        unsafeAtomicAdd(&stats[64 + t], sq);
    }
}

// ===========================================================================
// Fallback conv (proven): atomic scatter-add + separate stats. Used only if
// workspace is too small for the fused path (~42 MB).
// ===========================================================================
__global__ __launch_bounds__(256)
void conv_mfma(const __bf16* __restrict__ featb, const __bf16* __restrict__ wtb,
               const int* __restrict__ in_idx, const int* __restrict__ out_idx,
               float* __restrict__ out)
{
    constexpr int TP = 256;
    constexpr int STRIDE = 72;
    __shared__ __bf16 sA[TP * STRIDE];
    __shared__ int s_out[TP];

    const int k = blockIdx.y;
    const int tile_base = blockIdx.x * TP;
    const int t = threadIdx.x;
    const int lane = t & 63;
    const int wave = t >> 6;
    const int m16 = lane & 15;
    const int quad = lane >> 4;

    const __bf16* Wt = wtb + (size_t)k * C * C;
    bf16x8 bfrag[4][2];
#pragma unroll
    for (int nt = 0; nt < 4; ++nt)
#pragma unroll
        for (int kc = 0; kc < 2; ++kc)
            bfrag[nt][kc] = *(const bf16x8*)(Wt + (nt * 16 + m16) * C + kc * 32 + quad * 8);

    {
        const int pair = tile_base + t;
        s_out[t] = (pair < PPK) ? out_idx[(size_t)k * PPK + pair] : 0;
    }

    const int c8 = t & 7;
    const int r0 = t >> 3;
#pragma unroll
    for (int it = 0; it < 8; ++it) {
        const int r = r0 + it * 32;
        const int pair = tile_base + r;
        const int row = (pair < PPK) ? in_idx[(size_t)k * PPK + pair] : 0;
        const float4 v = *(const float4*)(featb + (size_t)row * C + c8 * 8);
        *(float4*)(sA + r * STRIDE + c8 * 8) = v;
    }
    __syncthreads();

    f32x4 acc[4][4] = {};
    const int mbase = wave * 64;
#pragma unroll
    for (int kc = 0; kc < 2; ++kc) {
        bf16x8 afrag[4];
#pragma unroll
        for (int mt = 0; mt < 4; ++mt)
            afrag[mt] = *(const bf16x8*)(sA + (mbase + mt * 16 + m16) * STRIDE + kc * 32 + quad * 8);
#pragma unroll
        for (int nt = 0; nt < 4; ++nt)
#pragma unroll
            for (int mt = 0; mt < 4; ++mt)
                acc[mt][nt] = __builtin_amdgcn_mfma_f32_16x16x32_bf16(
                    afrag[mt], bfrag[nt][kc], acc[mt][nt], 0, 0, 0);
    }

#pragma unroll
    for (int mt = 0; mt < 4; ++mt) {
#pragma unroll
        for (int reg = 0; reg < 4; ++reg) {
            const int r = mbase + mt * 16 + quad * 4 + reg;
            const int pair = tile_base + r;
            if (pair < PPK) {
                const int o = s_out[r];
                float* orow = out + (size_t)o * C + m16;
#pragma unroll
                for (int nt = 0; nt < 4; ++nt)
                    unsafeAtomicAdd(orow + nt * 16, acc[mt][nt][reg]);
            }
        }
    }
}

__global__ __launch_bounds__(256)
void stats_kernel(const float* __restrict__ out,
                  float* __restrict__ stats,
                  int rows_per_block)
{
    __shared__ float ssum[256];
    __shared__ float ssq[256];
    const int c   = threadIdx.x & 63;
    const int sub = threadIdx.x >> 6;
    const int row0 = blockIdx.x * rows_per_block;
    const int row1 = min(row0 + rows_per_block, N_VOX);
    float s = 0.f, q = 0.f;
    for (int r = row0 + sub; r < row1; r += 4) {
        const float v = out[(size_t)r * C + c];
        s += v;
        q += v * v;
    }
    ssum[threadIdx.x] = s;
    ssq[threadIdx.x]  = q;
    __syncthreads();
    if (sub == 0) {
        s = ssum[c] + ssum[64 + c] + ssum[128 + c] + ssum[192 + c];
        q = ssq[c]  + ssq[64 + c]  + ssq[128 + c]  + ssq[192 + c];
        unsafeAtomicAdd(&stats[c], s);
        unsafeAtomicAdd(&stats[64 + c], q);
    }
}

__global__ void finalize_params(const float* __restrict__ stats,
                                const float* __restrict__ gamma,
                                const float* __restrict__ beta,
                                float* __restrict__ ss)
{
    const int c = threadIdx.x;
    const float inv_n = 1.0f / (float)N_VOX;
    const float mean  = stats[c] * inv_n;
    const float var   = stats[64 + c] * inv_n - mean * mean;
    const float scale = rsqrtf(var + BN_EPS) * gamma[c];
    ss[c]      = scale;
    ss[64 + c] = beta[c] - mean * scale;
}

__global__ __launch_bounds__(256)
void norm_kernel(float* __restrict__ out, const float* __restrict__ ss)
{
    const size_t total4 = (size_t)N_VOX * C / 4;
    const size_t idx = (size_t)blockIdx.x * blockDim.x + threadIdx.x;
    if (idx >= total4) return;
    const int c4 = (int)(idx & 15);
    float4 v = ((const float4*)out)[idx];
    const float4 sc = ((const float4*)ss)[c4];
    const float4 sh = ((const float4*)(ss + 64))[c4];
    v.x = fmaxf(v.x * sc.x + sh.x, 0.f);
    v.y = fmaxf(v.y * sc.y + sh.y, 0.f);
    v.z = fmaxf(v.z * sc.z + sh.z, 0.f);
    v.w = fmaxf(v.w * sc.w + sh.w, 0.f);
    ((float4*)out)[idx] = v;
}

static inline size_t align_up(size_t x) { return (x + 255) & ~(size_t)255; }

extern "C" void kernel_launch(void* const* d_in, const int* in_sizes, int n_in,
                              void* d_out, int out_size, void* d_ws, size_t ws_size,
                              hipStream_t stream)
{
    const float* features = (const float*)d_in[0];
    const float* weight   = (const float*)d_in[1];
    // d_in[2] = bias: cancels under BN, unused.
    const float* gamma    = (const float*)d_in[3];
    const float* beta     = (const float*)d_in[4];
    const int*   in_idx   = (const int*)d_in[5];
    const int*   out_idx  = (const int*)d_in[6];
    float* out = (float*)d_out;

    // workspace layout
    char* base = (char*)d_ws;
    size_t off = 0;
    __bf16* featb = (__bf16*)(base + off); off += align_up((size_t)(N_VOX + 1) * C * 2); // +zero row
    __bf16* wtb   = (__bf16*)(base + off); off += align_up((size_t)KOFF * C * C * 2);
    float*  stats = (float*)(base + off);  off += align_up(128 * 4);
    float*  ss    = (float*)(base + off);  off += align_up(128 * 4);
    unsigned* counts  = (unsigned*)(base + off); off += align_up((size_t)NKEY * 4);
    unsigned* soff    = (unsigned*)(base + off); off += align_up((size_t)(NKEY + 1) * 4);
    unsigned* cursor  = (unsigned*)(base + off); off += align_up((size_t)NKEY * 4);
    unsigned* sorted_in = (unsigned*)(base + off); off += align_up((size_t)PADMAX * 4);
    unsigned char* sorted_ol = (unsigned char*)(base + off); off += align_up((size_t)PADMAX);
    const size_t needed = off;

    hipMemsetAsync(stats, 0, 128 * sizeof(float), stream);

    const size_t total4 = (size_t)N_VOX * C / 4;
    convert_features<<<(int)((total4 + 255) / 256), 256, 0, stream>>>(features, featb);
    convert_weight<<<KOFF, 256, 0, stream>>>(weight, wtb);

    if (ws_size >= needed) {
        // fused sorted path: sort pairs by (out_block,k), fused conv+reduce+stats
        hipMemsetAsync(counts, 0, (size_t)NKEY * 4, stream);
        hipMemsetAsync(featb + (size_t)N_VOX * C, 0, C * 2, stream);  // zero dummy row
        hist2<<<(NPAIR + 255) / 256, 256, 0, stream>>>(out_idx, counts);
        scan_pad<<<1, 256, 0, stream>>>(counts, soff, cursor);
        fill_kernel<<<(PADMAX + 255) / 256, 256, 0, stream>>>(sorted_in, sorted_ol);
        scatter_kernel<<<(NPAIR + 255) / 256, 256, 0, stream>>>(out_idx, in_idx, cursor,
                                                                sorted_in, sorted_ol);
        conv_fused<<<NBLK, 512, 0, stream>>>(featb, wtb, sorted_in, sorted_ol,
                                             soff, out, stats);
    } else {
        // fallback: proven atomic path
        hipMemsetAsync(out, 0, (size_t)N_VOX * C * sizeof(float), stream);
        dim3 cgrid((PPK + 255) / 256, KOFF);
        conv_mfma<<<cgrid, 256, 0, stream>>>(featb, wtb, in_idx, out_idx, out);
        const int rpb = (N_VOX + 511) / 512;
        stats_kernel<<<512, 256, 0, stream>>>(out, stats, rpb);
    }

    finalize_params<<<1, 64, 0, stream>>>(stats, gamma, beta, ss);

    norm_kernel<<<(int)((total4 + 255) / 256), 256, 0, stream>>>(out, ss);
}

// Round 6
// 1688.103 us; speedup vs baseline: 1.0041x; 1.0041x over previous
//
#include <hip/hip_runtime.h>
#include <hip/hip_bf16.h>

#define N_VOX 200000
#define KOFF 27
#define PPK 100000
#define C 64
#define BN_EPS 1e-5f

#define NBLK 782                      // ceil(N_VOX/256) out-voxel blocks
#define NKEY (NBLK * KOFF)            // 21114 (block,k) runs
#define NPAIR (KOFF * PPK)            // 2.7M
#define PADMAX (NPAIR + NKEY * 15)    // 3,016,710 max padded slots

typedef __bf16 bf16x8 __attribute__((ext_vector_type(8)));
typedef __bf16 bf16x4 __attribute__((ext_vector_type(4)));
typedef float f32x4 __attribute__((ext_vector_type(4)));

// ---------------------------------------------------------------------------
// features fp32 -> bf16 (RNE), vectorized. Also zeroes the dummy row N_VOX
// used by padded slots (block 0, threads 0..7).
// ---------------------------------------------------------------------------
__global__ __launch_bounds__(256)
void convert_features(const float* __restrict__ f, __bf16* __restrict__ fb)
{
    if (blockIdx.x == 0 && threadIdx.x < 8) {
        bf16x8 z = {};
        ((bf16x8*)(fb + (size_t)N_VOX * C))[threadIdx.x] = z;
    }
    const size_t total4 = (size_t)N_VOX * C / 4;
    const size_t i = (size_t)blockIdx.x * blockDim.x + threadIdx.x;
    if (i >= total4) return;
    const float4 v = ((const float4*)f)[i];
    bf16x4 o;
    o.x = (__bf16)v.x; o.y = (__bf16)v.y; o.z = (__bf16)v.z; o.w = (__bf16)v.w;
    ((bf16x4*)fb)[i] = o;
}

// weight [k][cin][cout] fp32 -> wt [k][cout][cin] bf16 (transposed).
// Also zeroes the (block,k) histogram bins (runs before hist2).
__global__ __launch_bounds__(256)
void convert_weight(const float* __restrict__ w, __bf16* __restrict__ wt,
                    unsigned* __restrict__ counts_or_null)
{
    const int k = blockIdx.x;
    const float* W = w + (size_t)k * C * C;
    __bf16* Wt = wt + (size_t)k * C * C;
    for (int idx = threadIdx.x; idx < C * C; idx += 256) {
        const int ci = idx >> 6, co = idx & 63;
        Wt[co * C + ci] = (__bf16)W[idx];
    }
    if (counts_or_null) {
        for (int i = blockIdx.x * 256 + threadIdx.x; i < NKEY; i += KOFF * 256)
            counts_or_null[i] = 0u;
    }
}

// ===========================================================================
// Pair sort by (out_block, k): histogram over 21114 bins -> padded scan
// (each run padded to x16 for whole MFMA tiles) -> scatter of
// (in_row u32, out_local u8).
// ===========================================================================
__global__ __launch_bounds__(256)
void hist2(const int* __restrict__ out_idx, unsigned* __restrict__ counts)
{
    const int i = blockIdx.x * 256 + threadIdx.x;
    if (i < NPAIR) {
        const int o = out_idx[i];
        const int k = i / PPK;
        atomicAdd(&counts[(o >> 8) * KOFF + k], 1u);
    }
}

// single-block scan of padded counts -> soff[NKEY+1]; seeds cursor; zeroes stats.
__global__ __launch_bounds__(256)
void scan_pad(const unsigned* __restrict__ counts, unsigned* __restrict__ soff,
              unsigned* __restrict__ cursor, float* __restrict__ stats)
{
    __shared__ unsigned sdata[256];
    const int t = threadIdx.x;
    if (t < 128) stats[t] = 0.f;
    const int CH = (NKEY + 255) / 256;   // 83
    const int i0 = t * CH;
    unsigned s = 0;
    for (int j = 0; j < CH; ++j) {
        const int i = i0 + j;
        if (i < NKEY) s += ((counts[i] + 15u) & ~15u);
    }
    sdata[t] = s;
    __syncthreads();
    for (int off = 1; off < 256; off <<= 1) {
        const unsigned a = (t >= off) ? sdata[t - off] : 0u;
        __syncthreads();
        sdata[t] += a;
        __syncthreads();
    }
    unsigned run = sdata[t] - s;   // exclusive prefix
    for (int j = 0; j < CH; ++j) {
        const int i = i0 + j;
        if (i < NKEY) {
            soff[i] = run;
            cursor[i] = run;
            run += ((counts[i] + 15u) & ~15u);
        }
    }
    if (t == 255) soff[NKEY] = run;
}

// pre-fill padded slots with dummy (in=N_VOX zero row, ol=0).
__global__ __launch_bounds__(256)
void fill_kernel(unsigned* __restrict__ sorted_in, unsigned char* __restrict__ sorted_ol)
{
    const int i = blockIdx.x * 256 + threadIdx.x;
    if (i < PADMAX) { sorted_in[i] = N_VOX; sorted_ol[i] = 0; }
}

__global__ __launch_bounds__(256)
void scatter_kernel(const int* __restrict__ out_idx, const int* __restrict__ in_idx,
                    unsigned* __restrict__ cursor, unsigned* __restrict__ sorted_in,
                    unsigned char* __restrict__ sorted_ol)
{
    const int i = blockIdx.x * 256 + threadIdx.x;
    if (i < NPAIR) {
        const int o = out_idx[i];
        const int k = i / PPK;
        const unsigned pos = atomicAdd(&cursor[(o >> 8) * KOFF + k], 1u);
        sorted_in[pos] = (unsigned)in_idx[i];
        sorted_ol[pos] = (unsigned char)(o & 255);
    }
}

// ===========================================================================
// FUSED conv+reduce+stats. Round-5 pathologies fixed:
//  (1) LDS f32 accumulation via __hip_atomic_fetch_add workgroup-scope
//      (round 5's generic atomicAdd lowered to a flat CAS loop: 192M slow
//      RMW round-trips = the 1205us stall; BANK_CONFLICT==0 was the tell).
//  (2) per-wave tile stream FLATTENED across k (cumulative tile index is
//      (skoff[k]-skoff[0])>>4 thanks to x16 padding) and software-pipelined
//      1-deep: next tile's index+feature gather issues before current tile's
//      MFMA + ds_add, so gather latency hides under compute.
// ===========================================================================
__global__ __launch_bounds__(512)
void conv_fused(const __bf16* __restrict__ featb, const __bf16* __restrict__ wtb,
                const unsigned* __restrict__ sorted_in,
                const unsigned char* __restrict__ sorted_ol,
                const unsigned* __restrict__ soff,
                float* __restrict__ out, float* __restrict__ stats)
{
    __shared__ float sout[256 * C];      // 64 KB accumulator tile
    __shared__ unsigned skoff[KOFF + 1];
    __shared__ float sstat[1024];

    const int b = blockIdx.x;
    const int t = threadIdx.x;

    {   // zero the accumulator
        f32x4* p = (f32x4*)sout;
        for (int i = t; i < 256 * C / 4; i += 512) p[i] = (f32x4){0.f, 0.f, 0.f, 0.f};
    }
    if (t < KOFF + 1) skoff[t] = soff[b * KOFF + t];
    __syncthreads();

    const int wave = t >> 6;
    const int lane = t & 63;
    const int m16 = lane & 15;
    const int quad = lane >> 4;
    const unsigned sk0 = skoff[0];

    // flattened per-wave tile iterator (wave-uniform state)
    int k = -1, lt = 0, ntk = 0;
    unsigned rb = 0;
    auto advance = [&]() -> bool {
        lt += 8;
        while (lt >= ntk) {
            if (++k >= KOFF) return false;
            rb = skoff[k];
            ntk = (int)((skoff[k + 1] - rb) >> 4);
            lt = (wave - (int)((rb - sk0) >> 4)) & 7;
        }
        return true;
    };

    bool more = advance();
    if (more) {
        int k_cur = k;
        unsigned tb_cur = rb + ((unsigned)lt << 4);
        {
            const unsigned rowA = sorted_in[tb_cur + m16];
            const __bf16* fr = featb + (size_t)rowA * C + quad * 8;
        }
        const unsigned row0 = sorted_in[tb_cur + m16];
        const __bf16* fr0 = featb + (size_t)row0 * C + quad * 8;
        bf16x8 a0 = *(const bf16x8*)fr0;
        bf16x8 a1 = *(const bf16x8*)(fr0 + 32);

        more = advance();
        int k_nxt = more ? k : k_cur;
        unsigned tb_nxt = more ? (rb + ((unsigned)lt << 4)) : tb_cur;

        int kb = -1;
        bf16x8 bfrag[4][2];
        for (;;) {
            if (k_cur != kb) {
                const __bf16* Wt = wtb + (size_t)k_cur * C * C;
#pragma unroll
                for (int nt = 0; nt < 4; ++nt)
#pragma unroll
                    for (int kc = 0; kc < 2; ++kc)
                        bfrag[nt][kc] = *(const bf16x8*)(Wt + (nt * 16 + m16) * C + kc * 32 + quad * 8);
                kb = k_cur;
            }
            // prefetch next tile's A fragments (hides gather under MFMA+ds_add)
            const unsigned rowN = sorted_in[tb_nxt + m16];
            const __bf16* frn = featb + (size_t)rowN * C + quad * 8;
            const bf16x8 n0 = *(const bf16x8*)frn;
            const bf16x8 n1 = *(const bf16x8*)(frn + 32);

            const int ol0 = sorted_ol[tb_cur + quad * 4 + 0];
            const int ol1 = sorted_ol[tb_cur + quad * 4 + 1];
            const int ol2 = sorted_ol[tb_cur + quad * 4 + 2];
            const int ol3 = sorted_ol[tb_cur + quad * 4 + 3];

            f32x4 acc[4] = {};
#pragma unroll
            for (int nt = 0; nt < 4; ++nt) {
                acc[nt] = __builtin_amdgcn_mfma_f32_16x16x32_bf16(a0, bfrag[nt][0], acc[nt], 0, 0, 0);
                acc[nt] = __builtin_amdgcn_mfma_f32_16x16x32_bf16(a1, bfrag[nt][1], acc[nt], 0, 0, 0);
            }
            // native ds_add_f32 accumulate: channel c = nt*16+m16, row ol
#pragma unroll
            for (int nt = 0; nt < 4; ++nt) {
                __hip_atomic_fetch_add(&sout[ol0 * C + nt * 16 + m16], acc[nt][0],
                                       __ATOMIC_RELAXED, __HIP_MEMORY_SCOPE_WORKGROUP);
                __hip_atomic_fetch_add(&sout[ol1 * C + nt * 16 + m16], acc[nt][1],
                                       __ATOMIC_RELAXED, __HIP_MEMORY_SCOPE_WORKGROUP);
                __hip_atomic_fetch_add(&sout[ol2 * C + nt * 16 + m16], acc[nt][2],
                                       __ATOMIC_RELAXED, __HIP_MEMORY_SCOPE_WORKGROUP);
                __hip_atomic_fetch_add(&sout[ol3 * C + nt * 16 + m16], acc[nt][3],
                                       __ATOMIC_RELAXED, __HIP_MEMORY_SCOPE_WORKGROUP);
            }
            if (!more) break;
            a0 = n0; a1 = n1;
            tb_cur = tb_nxt; k_cur = k_nxt;
            more = advance();
            k_nxt = more ? k : k_cur;
            tb_nxt = more ? (rb + ((unsigned)lt << 4)) : tb_cur;
        }
    }
    __syncthreads();

    // write final rows + per-channel stats partials
    const int row_cap = min(256, N_VOX - b * 256);
    const int c = t & 63;
    const int r0 = t >> 6;
    float s = 0.f, q = 0.f;
    for (int r = r0; r < row_cap; r += 8) {
        const float v = sout[r * C + c];
        out[((size_t)(b * 256 + r)) * C + c] = v;
        s += v; q += v * v;
    }
    sstat[t] = s;
    sstat[512 + t] = q;
    __syncthreads();
    if (t < C) {
        float ssum = 0.f, sq = 0.f;
#pragma unroll
        for (int u = 0; u < 8; ++u) {
            ssum += sstat[u * 64 + t];
            sq   += sstat[512 + u * 64 + t];
        }
        unsafeAtomicAdd(&stats[t], ssum);
        unsafeAtomicAdd(&stats[64 + t], sq);
    }
}

// ===========================================================================
// Fallback conv (proven): atomic scatter-add + separate stats. Used only if
// workspace is too small for the fused path (~42 MB).
// ===========================================================================
__global__ __launch_bounds__(256)
void conv_mfma(const __bf16* __restrict__ featb, const __bf16* __restrict__ wtb,
               const int* __restrict__ in_idx, const int* __restrict__ out_idx,
               float* __restrict__ out)
{
    constexpr int TP = 256;
    constexpr int STRIDE = 72;
    __shared__ __bf16 sA[TP * STRIDE];
    __shared__ int s_out[TP];

    const int k = blockIdx.y;
    const int tile_base = blockIdx.x * TP;
    const int t = threadIdx.x;
    const int lane = t & 63;
    const int wave = t >> 6;
    const int m16 = lane & 15;
    const int quad = lane >> 4;

    const __bf16* Wt = wtb + (size_t)k * C * C;
    bf16x8 bfrag[4][2];
#pragma unroll
    for (int nt = 0; nt < 4; ++nt)
#pragma unroll
        for (int kc = 0; kc < 2; ++kc)
            bfrag[nt][kc] = *(const bf16x8*)(Wt + (nt * 16 + m16) * C + kc * 32 + quad * 8);

    {
        const int pair = tile_base + t;
        s_out[t] = (pair < PPK) ? out_idx[(size_t)k * PPK + pair] : 0;
    }

    const int c8 = t & 7;
    const int r0 = t >> 3;
#pragma unroll
    for (int it = 0; it < 8; ++it) {
        const int r = r0 + it * 32;
        const int pair = tile_base + r;
        const int row = (pair < PPK) ? in_idx[(size_t)k * PPK + pair] : 0;
        const float4 v = *(const float4*)(featb + (size_t)row * C + c8 * 8);
        *(float4*)(sA + r * STRIDE + c8 * 8) = v;
    }
    __syncthreads();

    f32x4 acc[4][4] = {};
    const int mbase = wave * 64;
#pragma unroll
    for (int kc = 0; kc < 2; ++kc) {
        bf16x8 afrag[4];
#pragma unroll
        for (int mt = 0; mt < 4; ++mt)
            afrag[mt] = *(const bf16x8*)(sA + (mbase + mt * 16 + m16) * STRIDE + kc * 32 + quad * 8);
#pragma unroll
        for (int nt = 0; nt < 4; ++nt)
#pragma unroll
            for (int mt = 0; mt < 4; ++mt)
                acc[mt][nt] = __builtin_amdgcn_mfma_f32_16x16x32_bf16(
                    afrag[mt], bfrag[nt][kc], acc[mt][nt], 0, 0, 0);
    }

#pragma unroll
    for (int mt = 0; mt < 4; ++mt) {
#pragma unroll
        for (int reg = 0; reg < 4; ++reg) {
            const int r = mbase + mt * 16 + quad * 4 + reg;
            const int pair = tile_base + r;
            if (pair < PPK) {
                const int o = s_out[r];
                float* orow = out + (size_t)o * C + m16;
#pragma unroll
                for (int nt = 0; nt < 4; ++nt)
                    unsafeAtomicAdd(orow + nt * 16, acc[mt][nt][reg]);
            }
        }
    }
}

__global__ __launch_bounds__(256)
void stats_kernel(const float* __restrict__ out,
                  float* __restrict__ stats,
                  int rows_per_block)
{
    __shared__ float ssum[256];
    __shared__ float ssq[256];
    const int c   = threadIdx.x & 63;
    const int sub = threadIdx.x >> 6;
    const int row0 = blockIdx.x * rows_per_block;
    const int row1 = min(row0 + rows_per_block, N_VOX);
    float s = 0.f, q = 0.f;
    for (int r = row0 + sub; r < row1; r += 4) {
        const float v = out[(size_t)r * C + c];
        s += v;
        q += v * v;
    }
    ssum[threadIdx.x] = s;
    ssq[threadIdx.x]  = q;
    __syncthreads();
    if (sub == 0) {
        s = ssum[c] + ssum[64 + c] + ssum[128 + c] + ssum[192 + c];
        q = ssq[c]  + ssq[64 + c]  + ssq[128 + c]  + ssq[192 + c];
        unsafeAtomicAdd(&stats[c], s);
        unsafeAtomicAdd(&stats[64 + c], q);
    }
}

__global__ void finalize_params(const float* __restrict__ stats,
                                const float* __restrict__ gamma,
                                const float* __restrict__ beta,
                                float* __restrict__ ss)
{
    const int c = threadIdx.x;
    const float inv_n = 1.0f / (float)N_VOX;
    const float mean  = stats[c] * inv_n;
    const float var   = stats[64 + c] * inv_n - mean * mean;
    const float scale = rsqrtf(var + BN_EPS) * gamma[c];
    ss[c]      = scale;
    ss[64 + c] = beta[c] - mean * scale;
}

__global__ __launch_bounds__(256)
void norm_kernel(float* __restrict__ out, const float* __restrict__ ss)
{
    const size_t total4 = (size_t)N_VOX * C / 4;
    const size_t idx = (size_t)blockIdx.x * blockDim.x + threadIdx.x;
    if (idx >= total4) return;
    const int c4 = (int)(idx & 15);
    float4 v = ((const float4*)out)[idx];
    const float4 sc = ((const float4*)ss)[c4];
    const float4 sh = ((const float4*)(ss + 64))[c4];
    v.x = fmaxf(v.x * sc.x + sh.x, 0.f);
    v.y = fmaxf(v.y * sc.y + sh.y, 0.f);
    v.z = fmaxf(v.z * sc.z + sh.z, 0.f);
    v.w = fmaxf(v.w * sc.w + sh.w, 0.f);
    ((float4*)out)[idx] = v;
}

static inline size_t align_up(size_t x) { return (x + 255) & ~(size_t)255; }

extern "C" void kernel_launch(void* const* d_in, const int* in_sizes, int n_in,
                              void* d_out, int out_size, void* d_ws, size_t ws_size,
                              hipStream_t stream)
{
    const float* features = (const float*)d_in[0];
    const float* weight   = (const float*)d_in[1];
    // d_in[2] = bias: cancels under BN, unused.
    const float* gamma    = (const float*)d_in[3];
    const float* beta     = (const float*)d_in[4];
    const int*   in_idx   = (const int*)d_in[5];
    const int*   out_idx  = (const int*)d_in[6];
    float* out = (float*)d_out;

    // workspace layout
    char* base = (char*)d_ws;
    size_t off = 0;
    __bf16* featb = (__bf16*)(base + off); off += align_up((size_t)(N_VOX + 1) * C * 2); // +zero row
    __bf16* wtb   = (__bf16*)(base + off); off += align_up((size_t)KOFF * C * C * 2);
    float*  stats = (float*)(base + off);  off += align_up(128 * 4);
    float*  ss    = (float*)(base + off);  off += align_up(128 * 4);
    unsigned* counts  = (unsigned*)(base + off); off += align_up((size_t)NKEY * 4);
    unsigned* soff    = (unsigned*)(base + off); off += align_up((size_t)(NKEY + 1) * 4);
    unsigned* cursor  = (unsigned*)(base + off); off += align_up((size_t)NKEY * 4);
    unsigned* sorted_in = (unsigned*)(base + off); off += align_up((size_t)PADMAX * 4);
    unsigned char* sorted_ol = (unsigned char*)(base + off); off += align_up((size_t)PADMAX);
    const size_t needed = off;

    const bool fused = (ws_size >= needed);
    const size_t total4 = (size_t)N_VOX * C / 4;
    convert_features<<<(int)((total4 + 255) / 256), 256, 0, stream>>>(features, featb);
    convert_weight<<<KOFF, 256, 0, stream>>>(weight, wtb, fused ? counts : nullptr);

    if (fused) {
        // sorted fused path: sort pairs by (out_block,k), fused conv+reduce+stats
        hist2<<<(NPAIR + 255) / 256, 256, 0, stream>>>(out_idx, counts);
        scan_pad<<<1, 256, 0, stream>>>(counts, soff, cursor, stats);
        fill_kernel<<<(PADMAX + 255) / 256, 256, 0, stream>>>(sorted_in, sorted_ol);
        scatter_kernel<<<(NPAIR + 255) / 256, 256, 0, stream>>>(out_idx, in_idx, cursor,
                                                                sorted_in, sorted_ol);
        conv_fused<<<NBLK, 512, 0, stream>>>(featb, wtb, sorted_in, sorted_ol,
                                             soff, out, stats);
    } else {
        // fallback: proven atomic path
        hipMemsetAsync(stats, 0, 128 * sizeof(float), stream);
        hipMemsetAsync(out, 0, (size_t)N_VOX * C * sizeof(float), stream);
        dim3 cgrid((PPK + 255) / 256, KOFF);
        conv_mfma<<<cgrid, 256, 0, stream>>>(featb, wtb, in_idx, out_idx, out);
        const int rpb = (N_VOX + 511) / 512;
        stats_kernel<<<512, 256, 0, stream>>>(out, stats, rpb);
    }

    finalize_params<<<1, 64, 0, stream>>>(stats, gamma, beta, ss);

    norm_kernel<<<(int)((total4 + 255) / 256), 256, 0, stream>>>(out, ss);
}

// Round 7
// 627.458 us; speedup vs baseline: 2.7015x; 2.6904x over previous
//
#include <hip/hip_runtime.h>
#include <hip/hip_bf16.h>

#define N_VOX 200000
#define KOFF 27
#define PPK 100000
#define C 64
#define BN_EPS 1e-5f

typedef __bf16 bf16x8 __attribute__((ext_vector_type(8)));
typedef __bf16 bf16x4 __attribute__((ext_vector_type(4)));
typedef float f32x4 __attribute__((ext_vector_type(4)));

// ---------------------------------------------------------------------------
// features fp32 -> bf16 (RNE), vectorized: 1 float4 in -> 4 bf16 (8B) out.
// ---------------------------------------------------------------------------
__global__ __launch_bounds__(256)
void convert_features(const float* __restrict__ f, __bf16* __restrict__ fb)
{
    const size_t total4 = (size_t)N_VOX * C / 4;
    const size_t i = (size_t)blockIdx.x * blockDim.x + threadIdx.x;
    if (i >= total4) return;
    const float4 v = ((const float4*)f)[i];
    bf16x4 o;
    o.x = (__bf16)v.x; o.y = (__bf16)v.y; o.z = (__bf16)v.z; o.w = (__bf16)v.w;
    ((bf16x4*)fb)[i] = o;
}

// ---------------------------------------------------------------------------
// weight [k][cin][cout] fp32 -> wt [k][cout][cin] bf16 (transposed).
// Fused housekeeping (saves 2 memset dispatches): zeroes per-voxel histogram
// bins and the stats accumulator when the fused path is active.
// ---------------------------------------------------------------------------
__global__ __launch_bounds__(256)
void convert_weight(const float* __restrict__ w, __bf16* __restrict__ wt,
                    unsigned* __restrict__ counts_or_null,
                    float* __restrict__ stats)
{
    const int k = blockIdx.x;
    const float* W = w + (size_t)k * C * C;
    __bf16* Wt = wt + (size_t)k * C * C;
    for (int idx = threadIdx.x; idx < C * C; idx += 256) {
        const int ci = idx >> 6, co = idx & 63;
        Wt[co * C + ci] = (__bf16)W[idx];
    }
    if (counts_or_null) {
        for (int i = blockIdx.x * 256 + threadIdx.x; i < N_VOX; i += KOFF * 256)
            counts_or_null[i] = 0u;
        if (blockIdx.x == 0 && threadIdx.x < 128) stats[threadIdx.x] = 0.f;
    }
}

// ===========================================================================
// Rulebook inversion (per k-chunk): histogram capturing per-pair rank ->
// exclusive scan. The final slot add (rank + offsets[out]) is fused into
// conv_scatter as a plain latency-tolerant gather (NOT an atomic — rounds
// 2/3 proved the contended cursor RMW in conv costs 2.2 us/offset; round 4
// proved the precomputed-rank version runs at 7.05 us/offset).
// ===========================================================================
__global__ __launch_bounds__(256)
void hist_kernel(const int* __restrict__ out_idx, unsigned* __restrict__ counts,
                 unsigned* __restrict__ rank, int k0, int npair)
{
    const int i = blockIdx.x * 256 + threadIdx.x;
    if (i < npair) {
        const int o = out_idx[(size_t)k0 * PPK + i];
        rank[i] = atomicAdd(&counts[o], 1u);   // rank within voxel (this chunk)
    }
}

// exclusive scan of counts[200000] -> offsets; also RE-ZEROES counts so the
// next chunk's hist needs no memset. 1024 elems/block, 196 blocks.
__global__ __launch_bounds__(256)
void scan1(unsigned* __restrict__ counts, unsigned* __restrict__ offsets,
           unsigned* __restrict__ bsums)
{
    __shared__ unsigned sdata[256];
    const int t = threadIdx.x;
    const int base = blockIdx.x * 1024 + t * 4;
    unsigned v[4]; unsigned s = 0;
#pragma unroll
    for (int u = 0; u < 4; ++u) {
        const bool ok = (base + u < N_VOX);
        v[u] = ok ? counts[base + u] : 0u;
        if (ok) counts[base + u] = 0u;
        s += v[u];
    }
    sdata[t] = s;
    __syncthreads();
    for (int off = 1; off < 256; off <<= 1) {
        const unsigned add = (t >= off) ? sdata[t - off] : 0u;
        __syncthreads();
        sdata[t] += add;
        __syncthreads();
    }
    const unsigned incl = sdata[t];
    unsigned run = incl - s;          // exclusive prefix for this thread
    if (t == 255) bsums[blockIdx.x] = incl;
#pragma unroll
    for (int u = 0; u < 4; ++u) {
        if (base + u < N_VOX) offsets[base + u] = run;
        run += v[u];
    }
}

// Merged scan2+scan3 (saves a dispatch): each block covers 256 offsets
// elements, all sharing bsums index q = blockIdx>>2. Every wave redundantly
// computes sum(bsums[0..q-1]) (<=196 elems, L2-hot) and adds it.
__global__ __launch_bounds__(256)
void scan23(unsigned* __restrict__ offsets, const unsigned* __restrict__ bsums)
{
    const int i = blockIdx.x * 256 + threadIdx.x;
    const int q = blockIdx.x >> 2;
    const int lane = threadIdx.x & 63;
    unsigned s = 0;
    for (int j = lane; j < q; j += 64) s += bsums[j];
#pragma unroll
    for (int m = 1; m < 64; m <<= 1) s += __shfl_xor(s, m, 64);
    if (i < N_VOX) offsets[i] += s;
}

// ===========================================================================
// Conv via MFMA, scatter partial rows (bf16) to out-sorted slots. NO atomics:
// slot = rank[pair] (coalesced) + offsets[out] (L2-resident 800KB gather),
// issued at kernel start so its ~400cy chain hides under staging + MFMA.
// LDS: 32 KB XOR-swizzled A-tile (chunk ^= row&7) -> 5 blocks/CU, 0 bank
// conflicts (verified round 2). Plain write-back stores (NT hurt, round 2).
// Partial row layout c' = m16*4 + nt (true channel c = nt*16 + m16).
// ===========================================================================
__global__ __launch_bounds__(256)
void conv_scatter(const __bf16* __restrict__ featb, const __bf16* __restrict__ wtb,
                  const int* __restrict__ in_idx, const int* __restrict__ out_idx,
                  const unsigned* __restrict__ rank, const unsigned* __restrict__ offsets,
                  __bf16* __restrict__ partial, int k0)
{
    constexpr int TP = 256;       // pairs per tile
    __shared__ __bf16 sA[TP * 64];   // 32 KB exactly

    const int kloc = blockIdx.y;
    const int k = k0 + kloc;
    const int tile_base = blockIdx.x * TP;
    const int t = threadIdx.x;
    const int lane = t & 63;
    const int wave = t >> 6;
    const int m16 = lane & 15;    // A: pair-row in 16; B: cout; C/D: col
    const int quad = lane >> 4;   // 0..3

    // this thread's pair slot (consumed via shfl at the end)
    unsigned my_slot = 0u;
    {
        const int pair = tile_base + t;
        if (pair < PPK) {
            const int o = out_idx[(size_t)k * PPK + pair];
            my_slot = rank[(size_t)kloc * PPK + pair] + offsets[o];
        }
    }

    // B fragments from Wt[k][cout][cin]
    const __bf16* Wt = wtb + (size_t)k * C * C;
    bf16x8 bfrag[4][2];
#pragma unroll
    for (int nt = 0; nt < 4; ++nt)
#pragma unroll
        for (int kc = 0; kc < 2; ++kc)
            bfrag[nt][kc] = *(const bf16x8*)(Wt + (nt * 16 + m16) * C + kc * 32 + quad * 8);

    // stage gathered A rows: thread t loads row (t>>3)+32*it, 16B chunk (t&7),
    // stored at swizzled chunk (c8 ^ (r&7)).
    const int c8 = t & 7;
    const int r0 = t >> 3;
#pragma unroll
    for (int it = 0; it < 8; ++it) {
        const int r = r0 + it * 32;               // r&7 == r0&7
        const int pair = tile_base + r;
        const int row = (pair < PPK) ? in_idx[(size_t)k * PPK + pair] : 0;
        const float4 v = *(const float4*)(featb + (size_t)row * C + c8 * 8);
        *(float4*)(sA + r * 64 + ((c8 ^ (r0 & 7)) << 3)) = v;
    }
    __syncthreads();

    // MFMA: wave owns pairs [wave*64, wave*64+64). Read chunk (kc*4+quad)^(m16&7).
    f32x4 acc[4][4] = {};
    const int mbase = wave * 64;
#pragma unroll
    for (int kc = 0; kc < 2; ++kc) {
        bf16x8 afrag[4];
#pragma unroll
        for (int mt = 0; mt < 4; ++mt)
            afrag[mt] = *(const bf16x8*)(sA + (mbase + mt * 16 + m16) * 64
                                         + ((((kc << 2) | quad) ^ (m16 & 7)) << 3));
#pragma unroll
        for (int nt = 0; nt < 4; ++nt)
#pragma unroll
            for (int mt = 0; mt < 4; ++mt)
                acc[mt][nt] = __builtin_amdgcn_mfma_f32_16x16x32_bf16(
                    afrag[mt], bfrag[nt][kc], acc[mt][nt], 0, 0, 0);
    }

    // scatter partial rows: per (mt,reg) row, 16 lanes of a quad write the
    // full 128B bf16 row (8B per lane) at its out-sorted slot.
#pragma unroll
    for (int mt = 0; mt < 4; ++mt) {
#pragma unroll
        for (int reg = 0; reg < 4; ++reg) {
            const int rloc = mt * 16 + quad * 4 + reg;       // row within wave stripe
            const unsigned s = __shfl(my_slot, rloc, 64);
            const int pair = tile_base + mbase + rloc;
            if (pair < PPK) {
                bf16x4 pv;
                pv.x = (__bf16)acc[mt][0][reg];
                pv.y = (__bf16)acc[mt][1][reg];
                pv.z = (__bf16)acc[mt][2][reg];
                pv.w = (__bf16)acc[mt][3][reg];
                *(bf16x4*)(partial + (size_t)s * C + (m16 << 2)) = pv;
            }
        }
    }
}

// ---------------------------------------------------------------------------
// Reduce: one out row per WAVE, grid-stride. Lanes: e = lane>>4 covers slots
// beg+e, beg+e+4, ...; j = lane&15 covers permuted c' = 4j..4j+3 -> channels
// {j,16+j,32+j,48+j}. Cross-e sum via shfl_xor(16,32).
// On the LAST chunk, per-channel sum/sum-of-squares of the FINAL row values
// is folded in (replaces the separate stats_kernel pass + its dispatch).
// ---------------------------------------------------------------------------
__global__ __launch_bounds__(256)
void reduce_kernel(const __bf16* __restrict__ partial,
                   const unsigned* __restrict__ offsets,
                   float* __restrict__ out, float* __restrict__ stats,
                   const int first, const int last, const unsigned np)
{
    __shared__ float sstat[512];
    const int wave = threadIdx.x >> 6;
    const int lane = threadIdx.x & 63;
    const int e = lane >> 4;
    const int j = lane & 15;
    const int stride = gridDim.x * 4;
    float t0 = 0.f, t1 = 0.f, t2 = 0.f, t3 = 0.f;   // stats sums (e==0 lanes)
    float q0 = 0.f, q1 = 0.f, q2 = 0.f, q3 = 0.f;
    for (int o = blockIdx.x * 4 + wave; o < N_VOX; o += stride) {
        const unsigned beg = offsets[o];
        const unsigned end = (o + 1 < N_VOX) ? offsets[o + 1] : np;
        float a0 = 0.f, a1 = 0.f, a2 = 0.f, a3 = 0.f;
        for (unsigned s = beg + e; s < end; s += 4) {
            const bf16x4 v = *(const bf16x4*)(partial + (size_t)s * C + (j << 2));
            a0 += (float)v.x; a1 += (float)v.y; a2 += (float)v.z; a3 += (float)v.w;
        }
#pragma unroll
        for (int mask = 16; mask <= 32; mask <<= 1) {
            a0 += __shfl_xor(a0, mask, 64);
            a1 += __shfl_xor(a1, mask, 64);
            a2 += __shfl_xor(a2, mask, 64);
            a3 += __shfl_xor(a3, mask, 64);
        }
        if (e == 0) {
            float* orow = out + (size_t)o * C;
            if (!first) {
                a0 += orow[j]; a1 += orow[16 + j]; a2 += orow[32 + j]; a3 += orow[48 + j];
            }
            orow[j] = a0; orow[16 + j] = a1; orow[32 + j] = a2; orow[48 + j] = a3;
            if (last) {
                t0 += a0; q0 += a0 * a0;
                t1 += a1; q1 += a1 * a1;
                t2 += a2; q2 += a2 * a2;
                t3 += a3; q3 += a3 * a3;
            }
        }
    }
    if (last) {
        if (e == 0) {
            sstat[wave * 64 + j]            = t0;
            sstat[wave * 64 + 16 + j]       = t1;
            sstat[wave * 64 + 32 + j]       = t2;
            sstat[wave * 64 + 48 + j]       = t3;
            sstat[256 + wave * 64 + j]      = q0;
            sstat[256 + wave * 64 + 16 + j] = q1;
            sstat[256 + wave * 64 + 32 + j] = q2;
            sstat[256 + wave * 64 + 48 + j] = q3;
        }
        __syncthreads();
        const int t = threadIdx.x;
        if (t < 64) {
            const float ss = sstat[t] + sstat[64 + t] + sstat[128 + t] + sstat[192 + t];
            const float qq = sstat[256 + t] + sstat[320 + t] + sstat[384 + t] + sstat[448 + t];
            unsafeAtomicAdd(&stats[t], ss);
            unsafeAtomicAdd(&stats[64 + t], qq);
        }
    }
}

// ===========================================================================
// Fallback conv (proven): atomic scatter-add + separate stats. Used only if
// workspace is too small for the sorted-partial path.
// ===========================================================================
__global__ __launch_bounds__(256)
void conv_mfma(const __bf16* __restrict__ featb, const __bf16* __restrict__ wtb,
               const int* __restrict__ in_idx, const int* __restrict__ out_idx,
               float* __restrict__ out)
{
    constexpr int TP = 256;
    constexpr int STRIDE = 72;
    __shared__ __bf16 sA[TP * STRIDE];
    __shared__ int s_out[TP];

    const int k = blockIdx.y;
    const int tile_base = blockIdx.x * TP;
    const int t = threadIdx.x;
    const int lane = t & 63;
    const int wave = t >> 6;
    const int m16 = lane & 15;
    const int quad = lane >> 4;

    const __bf16* Wt = wtb + (size_t)k * C * C;
    bf16x8 bfrag[4][2];
#pragma unroll
    for (int nt = 0; nt < 4; ++nt)
#pragma unroll
        for (int kc = 0; kc < 2; ++kc)
            bfrag[nt][kc] = *(const bf16x8*)(Wt + (nt * 16 + m16) * C + kc * 32 + quad * 8);

    {
        const int pair = tile_base + t;
        s_out[t] = (pair < PPK) ? out_idx[(size_t)k * PPK + pair] : 0;
    }

    const int c8 = t & 7;
    const int r0 = t >> 3;
#pragma unroll
    for (int it = 0; it < 8; ++it) {
        const int r = r0 + it * 32;
        const int pair = tile_base + r;
        const int row = (pair < PPK) ? in_idx[(size_t)k * PPK + pair] : 0;
        const float4 v = *(const float4*)(featb + (size_t)row * C + c8 * 8);
        *(float4*)(sA + r * STRIDE + c8 * 8) = v;
    }
    __syncthreads();

    f32x4 acc[4][4] = {};
    const int mbase = wave * 64;
#pragma unroll
    for (int kc = 0; kc < 2; ++kc) {
        bf16x8 afrag[4];
#pragma unroll
        for (int mt = 0; mt < 4; ++mt)
            afrag[mt] = *(const bf16x8*)(sA + (mbase + mt * 16 + m16) * STRIDE + kc * 32 + quad * 8);
#pragma unroll
        for (int nt = 0; nt < 4; ++nt)
#pragma unroll
            for (int mt = 0; mt < 4; ++mt)
                acc[mt][nt] = __builtin_amdgcn_mfma_f32_16x16x32_bf16(
                    afrag[mt], bfrag[nt][kc], acc[mt][nt], 0, 0, 0);
    }

#pragma unroll
    for (int mt = 0; mt < 4; ++mt) {
#pragma unroll
        for (int reg = 0; reg < 4; ++reg) {
            const int r = mbase + mt * 16 + quad * 4 + reg;
            const int pair = tile_base + r;
            if (pair < PPK) {
                const int o = s_out[r];
                float* orow = out + (size_t)o * C + m16;
#pragma unroll
                for (int nt = 0; nt < 4; ++nt)
                    unsafeAtomicAdd(orow + nt * 16, acc[mt][nt][reg]);
            }
        }
    }
}

__global__ __launch_bounds__(256)
void stats_kernel(const float* __restrict__ out,
                  float* __restrict__ stats,
                  int rows_per_block)
{
    __shared__ float ssum[256];
    __shared__ float ssq[256];
    const int c   = threadIdx.x & 63;
    const int sub = threadIdx.x >> 6;
    const int row0 = blockIdx.x * rows_per_block;
    const int row1 = min(row0 + rows_per_block, N_VOX);
    float s = 0.f, q = 0.f;
    for (int r = row0 + sub; r < row1; r += 4) {
        const float v = out[(size_t)r * C + c];
        s += v;
        q += v * v;
    }
    ssum[threadIdx.x] = s;
    ssq[threadIdx.x]  = q;
    __syncthreads();
    if (sub == 0) {
        s = ssum[c] + ssum[64 + c] + ssum[128 + c] + ssum[192 + c];
        q = ssq[c]  + ssq[64 + c]  + ssq[128 + c]  + ssq[192 + c];
        unsafeAtomicAdd(&stats[c], s);
        unsafeAtomicAdd(&stats[64 + c], q);
    }
}

// ---------------------------------------------------------------------------
// Norm with finalize fused: each thread derives scale/shift for its 4
// channels from stats/gamma/beta directly (4 rsqrt per thread — trivial VALU;
// saves the separate finalize_params dispatch).
// ---------------------------------------------------------------------------
__global__ __launch_bounds__(256)
void norm_kernel(float* __restrict__ out, const float* __restrict__ stats,
                 const float* __restrict__ gamma, const float* __restrict__ beta)
{
    const size_t total4 = (size_t)N_VOX * C / 4;
    const size_t idx = (size_t)blockIdx.x * blockDim.x + threadIdx.x;
    if (idx >= total4) return;
    const int c4 = (int)(idx & 15);
    const float inv_n = 1.0f / (float)N_VOX;
    const float4 sm = ((const float4*)stats)[c4];
    const float4 sq = ((const float4*)(stats + 64))[c4];
    const float4 g  = ((const float4*)gamma)[c4];
    const float4 be = ((const float4*)beta)[c4];
    float4 v = ((const float4*)out)[idx];
    {
        const float mean = sm.x * inv_n;
        const float sc = rsqrtf(sq.x * inv_n - mean * mean + BN_EPS) * g.x;
        v.x = fmaxf(v.x * sc + (be.x - mean * sc), 0.f);
    }
    {
        const float mean = sm.y * inv_n;
        const float sc = rsqrtf(sq.y * inv_n - mean * mean + BN_EPS) * g.y;
        v.y = fmaxf(v.y * sc + (be.y - mean * sc), 0.f);
    }
    {
        const float mean = sm.z * inv_n;
        const float sc = rsqrtf(sq.z * inv_n - mean * mean + BN_EPS) * g.z;
        v.z = fmaxf(v.z * sc + (be.z - mean * sc), 0.f);
    }
    {
        const float mean = sm.w * inv_n;
        const float sc = rsqrtf(sq.w * inv_n - mean * mean + BN_EPS) * g.w;
        v.w = fmaxf(v.w * sc + (be.w - mean * sc), 0.f);
    }
    ((float4*)out)[idx] = v;
}

static inline size_t align_up(size_t x) { return (x + 255) & ~(size_t)255; }

extern "C" void kernel_launch(void* const* d_in, const int* in_sizes, int n_in,
                              void* d_out, int out_size, void* d_ws, size_t ws_size,
                              hipStream_t stream)
{
    const float* features = (const float*)d_in[0];
    const float* weight   = (const float*)d_in[1];
    // d_in[2] = bias: cancels under BN, unused.
    const float* gamma    = (const float*)d_in[3];
    const float* beta     = (const float*)d_in[4];
    const int*   in_idx   = (const int*)d_in[5];
    const int*   out_idx  = (const int*)d_in[6];
    float* out = (float*)d_out;

    // workspace layout (identical footprint to the proven round-4 version)
    char* base = (char*)d_ws;
    size_t off = 0;
    __bf16* featb = (__bf16*)(base + off); off += align_up((size_t)N_VOX * C * 2);
    __bf16* wtb   = (__bf16*)(base + off); off += align_up((size_t)KOFF * C * C * 2);
    float*  stats = (float*)(base + off);  off += align_up(128 * 4);
    float*  ss    = (float*)(base + off);  off += align_up(128 * 4);
    unsigned* counts  = (unsigned*)(base + off); off += align_up((size_t)N_VOX * 4);
    unsigned* offsets = (unsigned*)(base + off); off += align_up((size_t)N_VOX * 4);
    unsigned* bsums   = (unsigned*)(base + off); off += align_up(256 * 4);
    const size_t fixed = off;
    (void)ss;

    // per k-offset per chunk: rank u32[PPK] + partial bf16[PPK][64] = 132 B/pair
    int g_cap = 0;
    if (ws_size > fixed)
        g_cap = (int)((ws_size - fixed) / ((size_t)PPK * 132));
    if (g_cap > KOFF) g_cap = KOFF;

    const bool fused = (g_cap >= 2);

    const size_t total4 = (size_t)N_VOX * C / 4;
    convert_features<<<(int)((total4 + 255) / 256), 256, 0, stream>>>(features, featb);
    convert_weight<<<KOFF, 256, 0, stream>>>(weight, wtb,
                                             fused ? counts : nullptr, stats);

    if (fused) {
        // sorted-partial path: invert rulebook per chunk, no f32 atomics.
        const int G = (KOFF + g_cap - 1) / g_cap;
        const int gmax = (KOFF + G - 1) / G;
        unsigned* rank = (unsigned*)(base + off);
        __bf16* partial = (__bf16*)(base + off + align_up((size_t)gmax * PPK * 4));
        const int gbase_sz = KOFF / G, rem = KOFF % G;
        int k0 = 0;
        for (int ci = 0; ci < G; ++ci) {
            const int g = gbase_sz + (ci < rem ? 1 : 0);
            const int np = g * PPK;
            hist_kernel<<<(np + 255) / 256, 256, 0, stream>>>(out_idx, counts, rank, k0, np);
            scan1<<<(N_VOX + 1023) / 1024, 256, 0, stream>>>(counts, offsets, bsums);
            scan23<<<(N_VOX + 255) / 256, 256, 0, stream>>>(offsets, bsums);
            dim3 cgrid((PPK + 255) / 256, g);
            conv_scatter<<<cgrid, 256, 0, stream>>>(featb, wtb, in_idx, out_idx,
                                                    rank, offsets, partial, k0);
            reduce_kernel<<<1024, 256, 0, stream>>>(partial, offsets, out, stats,
                                                    ci == 0 ? 1 : 0,
                                                    ci == G - 1 ? 1 : 0,
                                                    (unsigned)np);
            k0 += g;
        }
    } else {
        // fallback: proven atomic path
        hipMemsetAsync(stats, 0, 128 * sizeof(float), stream);
        hipMemsetAsync(out, 0, (size_t)N_VOX * C * sizeof(float), stream);
        dim3 cgrid((PPK + 255) / 256, KOFF);
        conv_mfma<<<cgrid, 256, 0, stream>>>(featb, wtb, in_idx, out_idx, out);
        const int rpb = (N_VOX + 511) / 512;
        stats_kernel<<<512, 256, 0, stream>>>(out, stats, rpb);
    }

    norm_kernel<<<(int)((total4 + 255) / 256), 256, 0, stream>>>(out, stats, gamma, beta);
}

// Round 8
// 617.704 us; speedup vs baseline: 2.7442x; 1.0158x over previous
//
#include <hip/hip_runtime.h>
#include <hip/hip_bf16.h>

#define N_VOX 200000
#define KOFF 27
#define PPK 100000
#define C 64
#define BN_EPS 1e-5f

typedef __bf16 bf16x8 __attribute__((ext_vector_type(8)));
typedef __bf16 bf16x4 __attribute__((ext_vector_type(4)));
typedef float f32x4 __attribute__((ext_vector_type(4)));

// ---------------------------------------------------------------------------
// features fp32 -> bf16 (RNE), vectorized: 1 float4 in -> 4 bf16 (8B) out.
// ---------------------------------------------------------------------------
__global__ __launch_bounds__(256)
void convert_features(const float* __restrict__ f, __bf16* __restrict__ fb)
{
    const size_t total4 = (size_t)N_VOX * C / 4;
    const size_t i = (size_t)blockIdx.x * blockDim.x + threadIdx.x;
    if (i >= total4) return;
    const float4 v = ((const float4*)f)[i];
    bf16x4 o;
    o.x = (__bf16)v.x; o.y = (__bf16)v.y; o.z = (__bf16)v.z; o.w = (__bf16)v.w;
    ((bf16x4*)fb)[i] = o;
}

// ---------------------------------------------------------------------------
// weight [k][cin][cout] fp32 -> wt [k][cout][cin] bf16 (transposed).
// Fused housekeeping: zeroes histogram bins and stats (saves 2 memsets).
// ---------------------------------------------------------------------------
__global__ __launch_bounds__(256)
void convert_weight(const float* __restrict__ w, __bf16* __restrict__ wt,
                    unsigned* __restrict__ counts_or_null,
                    float* __restrict__ stats)
{
    const int k = blockIdx.x;
    const float* W = w + (size_t)k * C * C;
    __bf16* Wt = wt + (size_t)k * C * C;
    for (int idx = threadIdx.x; idx < C * C; idx += 256) {
        const int ci = idx >> 6, co = idx & 63;
        Wt[co * C + ci] = (__bf16)W[idx];
    }
    if (counts_or_null) {
        for (int i = blockIdx.x * 256 + threadIdx.x; i < N_VOX; i += KOFF * 256)
            counts_or_null[i] = 0u;
        if (blockIdx.x == 0 && threadIdx.x < 128) stats[threadIdx.x] = 0.f;
    }
}

// ===========================================================================
// Rulebook inversion (per k-chunk): histogram capturing per-pair rank ->
// exclusive scan. Slot add (rank + offsets[out]) fused into conv_scatter as
// a plain gather (atomics stay in latency-tolerant streaming passes).
// ===========================================================================
__global__ __launch_bounds__(256)
void hist_kernel(const int* __restrict__ out_idx, unsigned* __restrict__ counts,
                 unsigned* __restrict__ rank, int k0, int npair)
{
    const int i = blockIdx.x * 256 + threadIdx.x;
    if (i < npair) {
        const int o = out_idx[(size_t)k0 * PPK + i];
        rank[i] = atomicAdd(&counts[o], 1u);   // rank within voxel (this chunk)
    }
}

// exclusive scan of counts[200000] -> offsets; re-zeroes counts for next chunk.
__global__ __launch_bounds__(256)
void scan1(unsigned* __restrict__ counts, unsigned* __restrict__ offsets,
           unsigned* __restrict__ bsums)
{
    __shared__ unsigned sdata[256];
    const int t = threadIdx.x;
    const int base = blockIdx.x * 1024 + t * 4;
    unsigned v[4]; unsigned s = 0;
#pragma unroll
    for (int u = 0; u < 4; ++u) {
        const bool ok = (base + u < N_VOX);
        v[u] = ok ? counts[base + u] : 0u;
        if (ok) counts[base + u] = 0u;
        s += v[u];
    }
    sdata[t] = s;
    __syncthreads();
    for (int off = 1; off < 256; off <<= 1) {
        const unsigned add = (t >= off) ? sdata[t - off] : 0u;
        __syncthreads();
        sdata[t] += add;
        __syncthreads();
    }
    const unsigned incl = sdata[t];
    unsigned run = incl - s;          // exclusive prefix for this thread
    if (t == 255) bsums[blockIdx.x] = incl;
#pragma unroll
    for (int u = 0; u < 4; ++u) {
        if (base + u < N_VOX) offsets[base + u] = run;
        run += v[u];
    }
}

// Merged scan2+scan3: each block redundantly sums bsums[0..q-1] (L2-hot).
__global__ __launch_bounds__(256)
void scan23(unsigned* __restrict__ offsets, const unsigned* __restrict__ bsums)
{
    const int i = blockIdx.x * 256 + threadIdx.x;
    const int q = blockIdx.x >> 2;
    const int lane = threadIdx.x & 63;
    unsigned s = 0;
    for (int j = lane; j < q; j += 64) s += bsums[j];
#pragma unroll
    for (int m = 1; m < 64; m <<= 1) s += __shfl_xor(s, m, 64);
    if (i < N_VOX) offsets[i] += s;
}

// ===========================================================================
// Conv via MFMA, scatter partial rows (bf16) to out-sorted slots. NO atomics:
// slot = rank[pair] + offsets[out], issued at kernel start. 32 KB XOR-
// swizzled LDS A-tile, 0 bank conflicts. Runs at the random-128B-write
// HBM rate (~2.8 TB/s) — near its structural ceiling.
// Partial row layout c' = m16*4 + nt (true channel c = nt*16 + m16).
// ===========================================================================
__global__ __launch_bounds__(256)
void conv_scatter(const __bf16* __restrict__ featb, const __bf16* __restrict__ wtb,
                  const int* __restrict__ in_idx, const int* __restrict__ out_idx,
                  const unsigned* __restrict__ rank, const unsigned* __restrict__ offsets,
                  __bf16* __restrict__ partial, int k0)
{
    constexpr int TP = 256;       // pairs per tile
    __shared__ __bf16 sA[TP * 64];   // 32 KB exactly

    const int kloc = blockIdx.y;
    const int k = k0 + kloc;
    const int tile_base = blockIdx.x * TP;
    const int t = threadIdx.x;
    const int lane = t & 63;
    const int wave = t >> 6;
    const int m16 = lane & 15;    // A: pair-row in 16; B: cout; C/D: col
    const int quad = lane >> 4;   // 0..3

    // this thread's pair slot (consumed via shfl at the end)
    unsigned my_slot = 0u;
    {
        const int pair = tile_base + t;
        if (pair < PPK) {
            const int o = out_idx[(size_t)k * PPK + pair];
            my_slot = rank[(size_t)kloc * PPK + pair] + offsets[o];
        }
    }

    // B fragments from Wt[k][cout][cin]
    const __bf16* Wt = wtb + (size_t)k * C * C;
    bf16x8 bfrag[4][2];
#pragma unroll
    for (int nt = 0; nt < 4; ++nt)
#pragma unroll
        for (int kc = 0; kc < 2; ++kc)
            bfrag[nt][kc] = *(const bf16x8*)(Wt + (nt * 16 + m16) * C + kc * 32 + quad * 8);

    // stage gathered A rows: thread t loads row (t>>3)+32*it, 16B chunk (t&7),
    // stored at swizzled chunk (c8 ^ (r&7)).
    const int c8 = t & 7;
    const int r0 = t >> 3;
#pragma unroll
    for (int it = 0; it < 8; ++it) {
        const int r = r0 + it * 32;               // r&7 == r0&7
        const int pair = tile_base + r;
        const int row = (pair < PPK) ? in_idx[(size_t)k * PPK + pair] : 0;
        const float4 v = *(const float4*)(featb + (size_t)row * C + c8 * 8);
        *(float4*)(sA + r * 64 + ((c8 ^ (r0 & 7)) << 3)) = v;
    }
    __syncthreads();

    // MFMA: wave owns pairs [wave*64, wave*64+64). Read chunk (kc*4+quad)^(m16&7).
    f32x4 acc[4][4] = {};
    const int mbase = wave * 64;
#pragma unroll
    for (int kc = 0; kc < 2; ++kc) {
        bf16x8 afrag[4];
#pragma unroll
        for (int mt = 0; mt < 4; ++mt)
            afrag[mt] = *(const bf16x8*)(sA + (mbase + mt * 16 + m16) * 64
                                         + ((((kc << 2) | quad) ^ (m16 & 7)) << 3));
#pragma unroll
        for (int nt = 0; nt < 4; ++nt)
#pragma unroll
            for (int mt = 0; mt < 4; ++mt)
                acc[mt][nt] = __builtin_amdgcn_mfma_f32_16x16x32_bf16(
                    afrag[mt], bfrag[nt][kc], acc[mt][nt], 0, 0, 0);
    }

    // scatter partial rows: per (mt,reg) row, 16 lanes of a quad write the
    // full 128B bf16 row (8B per lane) at its out-sorted slot.
#pragma unroll
    for (int mt = 0; mt < 4; ++mt) {
#pragma unroll
        for (int reg = 0; reg < 4; ++reg) {
            const int rloc = mt * 16 + quad * 4 + reg;       // row within wave stripe
            const unsigned s = __shfl(my_slot, rloc, 64);
            const int pair = tile_base + mbase + rloc;
            if (pair < PPK) {
                bf16x4 pv;
                pv.x = (__bf16)acc[mt][0][reg];
                pv.y = (__bf16)acc[mt][1][reg];
                pv.z = (__bf16)acc[mt][2][reg];
                pv.w = (__bf16)acc[mt][3][reg];
                *(bf16x4*)(partial + (size_t)s * C + (m16 << 2)) = pv;
            }
        }
    }
}

// ---------------------------------------------------------------------------
// Reduce: one out row per WAVE, grid-stride. Round-7 counters showed this
// latency-bound (110us, 18.6% HBM, occ 38%): now e = lane>>3 covers 8 slots
// x bf16x8 (16B/lane) = 1KB/wave/iter (2x width — mean 6.75-slot voxel done
// in ONE iteration), grid 2048 (2x waves in flight), and the out-row RMW
// operands prefetch before the slot loop. Lane j = lane&7 covers permuted
// c' = 8j..8j+7 -> true channel c = (p&3)*16 + (p>>2). Cross-e sum via
// shfl_xor(8,16,32). Last chunk folds per-channel sum/sumsq stats.
// ---------------------------------------------------------------------------
__global__ __launch_bounds__(256)
void reduce_kernel(const __bf16* __restrict__ partial,
                   const unsigned* __restrict__ offsets,
                   float* __restrict__ out, float* __restrict__ stats,
                   const int first, const int last, const unsigned np)
{
    __shared__ float sstat[512];
    const int wave = threadIdx.x >> 6;
    const int lane = threadIdx.x & 63;
    const int e = lane >> 3;      // 0..7: slot sub-lane
    const int j = lane & 7;       // channel-8 group
    const int stride = gridDim.x * 4;
    float tacc[8] = {0.f, 0.f, 0.f, 0.f, 0.f, 0.f, 0.f, 0.f};
    float qacc[8] = {0.f, 0.f, 0.f, 0.f, 0.f, 0.f, 0.f, 0.f};
    // true channel for permuted index p = 8j+i
    int cmap[8];
#pragma unroll
    for (int i = 0; i < 8; ++i) {
        const int p = j * 8 + i;
        cmap[i] = (p & 3) * 16 + (p >> 2);
    }
    for (int o = blockIdx.x * 4 + wave; o < N_VOX; o += stride) {
        const unsigned beg = offsets[o];
        const unsigned end = (o + 1 < N_VOX) ? offsets[o + 1] : np;
        float* orow = out + (size_t)o * C;
        // prefetch RMW operands (hides under the slot loop)
        float prev[8];
        if (!first && e == 0) {
#pragma unroll
            for (int i = 0; i < 8; ++i) prev[i] = orow[cmap[i]];
        }
        float a[8] = {0.f, 0.f, 0.f, 0.f, 0.f, 0.f, 0.f, 0.f};
        for (unsigned s = beg + e; s < end; s += 8) {
            const bf16x8 v = *(const bf16x8*)(partial + (size_t)s * C + (j << 3));
#pragma unroll
            for (int i = 0; i < 8; ++i) a[i] += (float)v[i];
        }
#pragma unroll
        for (int m = 8; m <= 32; m <<= 1)
#pragma unroll
            for (int i = 0; i < 8; ++i) a[i] += __shfl_xor(a[i], m, 64);
        if (e == 0) {
#pragma unroll
            for (int i = 0; i < 8; ++i) {
                float v = a[i];
                if (!first) v += prev[i];
                orow[cmap[i]] = v;
                if (last) { tacc[i] += v; qacc[i] += v * v; }
            }
        }
    }
    if (last) {
        if (e == 0) {
#pragma unroll
            for (int i = 0; i < 8; ++i) {
                sstat[wave * 64 + cmap[i]]       = tacc[i];
                sstat[256 + wave * 64 + cmap[i]] = qacc[i];
            }
        }
        __syncthreads();
        const int t = threadIdx.x;
        if (t < 64) {
            const float ss = sstat[t] + sstat[64 + t] + sstat[128 + t] + sstat[192 + t];
            const float qq = sstat[256 + t] + sstat[320 + t] + sstat[384 + t] + sstat[448 + t];
            unsafeAtomicAdd(&stats[t], ss);
            unsafeAtomicAdd(&stats[64 + t], qq);
        }
    }
}

// ===========================================================================
// Fallback conv (proven): atomic scatter-add + separate stats. Used only if
// workspace is too small for the sorted-partial path.
// ===========================================================================
__global__ __launch_bounds__(256)
void conv_mfma(const __bf16* __restrict__ featb, const __bf16* __restrict__ wtb,
               const int* __restrict__ in_idx, const int* __restrict__ out_idx,
               float* __restrict__ out)
{
    constexpr int TP = 256;
    constexpr int STRIDE = 72;
    __shared__ __bf16 sA[TP * STRIDE];
    __shared__ int s_out[TP];

    const int k = blockIdx.y;
    const int tile_base = blockIdx.x * TP;
    const int t = threadIdx.x;
    const int lane = t & 63;
    const int wave = t >> 6;
    const int m16 = lane & 15;
    const int quad = lane >> 4;

    const __bf16* Wt = wtb + (size_t)k * C * C;
    bf16x8 bfrag[4][2];
#pragma unroll
    for (int nt = 0; nt < 4; ++nt)
#pragma unroll
        for (int kc = 0; kc < 2; ++kc)
            bfrag[nt][kc] = *(const bf16x8*)(Wt + (nt * 16 + m16) * C + kc * 32 + quad * 8);

    {
        const int pair = tile_base + t;
        s_out[t] = (pair < PPK) ? out_idx[(size_t)k * PPK + pair] : 0;
    }

    const int c8 = t & 7;
    const int r0 = t >> 3;
#pragma unroll
    for (int it = 0; it < 8; ++it) {
        const int r = r0 + it * 32;
        const int pair = tile_base + r;
        const int row = (pair < PPK) ? in_idx[(size_t)k * PPK + pair] : 0;
        const float4 v = *(const float4*)(featb + (size_t)row * C + c8 * 8);
        *(float4*)(sA + r * STRIDE + c8 * 8) = v;
    }
    __syncthreads();

    f32x4 acc[4][4] = {};
    const int mbase = wave * 64;
#pragma unroll
    for (int kc = 0; kc < 2; ++kc) {
        bf16x8 afrag[4];
#pragma unroll
        for (int mt = 0; mt < 4; ++mt)
            afrag[mt] = *(const bf16x8*)(sA + (mbase + mt * 16 + m16) * STRIDE + kc * 32 + quad * 8);
#pragma unroll
        for (int nt = 0; nt < 4; ++nt)
#pragma unroll
            for (int mt = 0; mt < 4; ++mt)
                acc[mt][nt] = __builtin_amdgcn_mfma_f32_16x16x32_bf16(
                    afrag[mt], bfrag[nt][kc], acc[mt][nt], 0, 0, 0);
    }

#pragma unroll
    for (int mt = 0; mt < 4; ++mt) {
#pragma unroll
        for (int reg = 0; reg < 4; ++reg) {
            const int r = mbase + mt * 16 + quad * 4 + reg;
            const int pair = tile_base + r;
            if (pair < PPK) {
                const int o = s_out[r];
                float* orow = out + (size_t)o * C + m16;
#pragma unroll
                for (int nt = 0; nt < 4; ++nt)
                    unsafeAtomicAdd(orow + nt * 16, acc[mt][nt][reg]);
            }
        }
    }
}

__global__ __launch_bounds__(256)
void stats_kernel(const float* __restrict__ out,
                  float* __restrict__ stats,
                  int rows_per_block)
{
    __shared__ float ssum[256];
    __shared__ float ssq[256];
    const int c   = threadIdx.x & 63;
    const int sub = threadIdx.x >> 6;
    const int row0 = blockIdx.x * rows_per_block;
    const int row1 = min(row0 + rows_per_block, N_VOX);
    float s = 0.f, q = 0.f;
    for (int r = row0 + sub; r < row1; r += 4) {
        const float v = out[(size_t)r * C + c];
        s += v;
        q += v * v;
    }
    ssum[threadIdx.x] = s;
    ssq[threadIdx.x]  = q;
    __syncthreads();
    if (sub == 0) {
        s = ssum[c] + ssum[64 + c] + ssum[128 + c] + ssum[192 + c];
        q = ssq[c]  + ssq[64 + c]  + ssq[128 + c]  + ssq[192 + c];
        unsafeAtomicAdd(&stats[c], s);
        unsafeAtomicAdd(&stats[64 + c], q);
    }
}

// ---------------------------------------------------------------------------
// Norm with finalize fused: per-thread scale/shift from stats (4 rsqrt).
// ---------------------------------------------------------------------------
__global__ __launch_bounds__(256)
void norm_kernel(float* __restrict__ out, const float* __restrict__ stats,
                 const float* __restrict__ gamma, const float* __restrict__ beta)
{
    const size_t total4 = (size_t)N_VOX * C / 4;
    const size_t idx = (size_t)blockIdx.x * blockDim.x + threadIdx.x;
    if (idx >= total4) return;
    const int c4 = (int)(idx & 15);
    const float inv_n = 1.0f / (float)N_VOX;
    const float4 sm = ((const float4*)stats)[c4];
    const float4 sq = ((const float4*)(stats + 64))[c4];
    const float4 g  = ((const float4*)gamma)[c4];
    const float4 be = ((const float4*)beta)[c4];
    float4 v = ((const float4*)out)[idx];
    {
        const float mean = sm.x * inv_n;
        const float sc = rsqrtf(sq.x * inv_n - mean * mean + BN_EPS) * g.x;
        v.x = fmaxf(v.x * sc + (be.x - mean * sc), 0.f);
    }
    {
        const float mean = sm.y * inv_n;
        const float sc = rsqrtf(sq.y * inv_n - mean * mean + BN_EPS) * g.y;
        v.y = fmaxf(v.y * sc + (be.y - mean * sc), 0.f);
    }
    {
        const float mean = sm.z * inv_n;
        const float sc = rsqrtf(sq.z * inv_n - mean * mean + BN_EPS) * g.z;
        v.z = fmaxf(v.z * sc + (be.z - mean * sc), 0.f);
    }
    {
        const float mean = sm.w * inv_n;
        const float sc = rsqrtf(sq.w * inv_n - mean * mean + BN_EPS) * g.w;
        v.w = fmaxf(v.w * sc + (be.w - mean * sc), 0.f);
    }
    ((float4*)out)[idx] = v;
}

static inline size_t align_up(size_t x) { return (x + 255) & ~(size_t)255; }

extern "C" void kernel_launch(void* const* d_in, const int* in_sizes, int n_in,
                              void* d_out, int out_size, void* d_ws, size_t ws_size,
                              hipStream_t stream)
{
    const float* features = (const float*)d_in[0];
    const float* weight   = (const float*)d_in[1];
    // d_in[2] = bias: cancels under BN, unused.
    const float* gamma    = (const float*)d_in[3];
    const float* beta     = (const float*)d_in[4];
    const int*   in_idx   = (const int*)d_in[5];
    const int*   out_idx  = (const int*)d_in[6];
    float* out = (float*)d_out;

    // workspace layout (identical footprint to the proven round-4 version)
    char* base = (char*)d_ws;
    size_t off = 0;
    __bf16* featb = (__bf16*)(base + off); off += align_up((size_t)N_VOX * C * 2);
    __bf16* wtb   = (__bf16*)(base + off); off += align_up((size_t)KOFF * C * C * 2);
    float*  stats = (float*)(base + off);  off += align_up(128 * 4);
    float*  ss    = (float*)(base + off);  off += align_up(128 * 4);
    unsigned* counts  = (unsigned*)(base + off); off += align_up((size_t)N_VOX * 4);
    unsigned* offsets = (unsigned*)(base + off); off += align_up((size_t)N_VOX * 4);
    unsigned* bsums   = (unsigned*)(base + off); off += align_up(256 * 4);
    const size_t fixed = off;
    (void)ss;

    // per k-offset per chunk: rank u32[PPK] + partial bf16[PPK][64] = 132 B/pair
    int g_cap = 0;
    if (ws_size > fixed)
        g_cap = (int)((ws_size - fixed) / ((size_t)PPK * 132));
    if (g_cap > KOFF) g_cap = KOFF;

    const bool fused = (g_cap >= 2);

    const size_t total4 = (size_t)N_VOX * C / 4;
    convert_features<<<(int)((total4 + 255) / 256), 256, 0, stream>>>(features, featb);
    convert_weight<<<KOFF, 256, 0, stream>>>(weight, wtb,
                                             fused ? counts : nullptr, stats);

    if (fused) {
        // sorted-partial path: invert rulebook per chunk, no f32 atomics.
        const int G = (KOFF + g_cap - 1) / g_cap;
        const int gmax = (KOFF + G - 1) / G;
        unsigned* rank = (unsigned*)(base + off);
        __bf16* partial = (__bf16*)(base + off + align_up((size_t)gmax * PPK * 4));
        const int gbase_sz = KOFF / G, rem = KOFF % G;
        int k0 = 0;
        for (int ci = 0; ci < G; ++ci) {
            const int g = gbase_sz + (ci < rem ? 1 : 0);
            const int np = g * PPK;
            hist_kernel<<<(np + 255) / 256, 256, 0, stream>>>(out_idx, counts, rank, k0, np);
            scan1<<<(N_VOX + 1023) / 1024, 256, 0, stream>>>(counts, offsets, bsums);
            scan23<<<(N_VOX + 255) / 256, 256, 0, stream>>>(offsets, bsums);
            dim3 cgrid((PPK + 255) / 256, g);
            conv_scatter<<<cgrid, 256, 0, stream>>>(featb, wtb, in_idx, out_idx,
                                                    rank, offsets, partial, k0);
            reduce_kernel<<<2048, 256, 0, stream>>>(partial, offsets, out, stats,
                                                    ci == 0 ? 1 : 0,
                                                    ci == G - 1 ? 1 : 0,
                                                    (unsigned)np);
            k0 += g;
        }
    } else {
        // fallback: proven atomic path
        hipMemsetAsync(stats, 0, 128 * sizeof(float), stream);
        hipMemsetAsync(out, 0, (size_t)N_VOX * C * sizeof(float), stream);
        dim3 cgrid((PPK + 255) / 256, KOFF);
        conv_mfma<<<cgrid, 256, 0, stream>>>(featb, wtb, in_idx, out_idx, out);
        const int rpb = (N_VOX + 511) / 512;
        stats_kernel<<<512, 256, 0, stream>>>(out, stats, rpb);
    }

    norm_kernel<<<(int)((total4 + 255) / 256), 256, 0, stream>>>(out, stats, gamma, beta);
}